// Round 15
// baseline (137.152 us; speedup 1.0000x reference)
//
#include <hip/hip_runtime.h>
#include <stdint.h>

// SimCLR loss, B=4096, D=512, TAU=0.1.  out[0]=loss, out[1]=acc(%).
//
// Round 25: R24 with ONE change -- __launch_bounds__(512, 1).
// R24's (512,2) implied a 128-VGPR cap; the 8-wave block's live set is
// slightly over 128 -> ~36MB scratch (WRITE 41.7MB, MfmaUtil 0.26%) --
// fourth spill of the session, and it invalidated the residency experiment.
// (512,1) -> cap 256; allocator lands at the true live set (~132-170),
// 2 waves/SIMD fit -> 8 waves/CU GUARANTEED per resident block, no spill.
// This is the clean test of the session's core finding: effective
// concurrency ~1 block (4 waves)/CU = 1 wave/SIMD = zero intra-SIMD
// latency hiding = all pipes <30% at the ~48.5us tiles floor.
//  - 32 panels x 256 rows; block = 8 waves x 32 rows, chunk = 4 tiles ->
//    528 blocks, ALL exactly 4 tiles (balanced); ~2.06 rounds/CU.
//  - per-wave code = R21 (frag pattern, 5-bit-swizzled LDS reads, 16
//    MFMA/tile, reg row-accum, one block-end reduce).
//  - col partials: 16 slices [16][64], merged by tid<64 after barrier.
//  - epilogue max-variant split (row-max only I<16, col-max only j<64).
//  - LDS 40KB (32 tile + 8 partials).

#define BN 4096
#define DK 512            // K elements = bytes per row in fp8
#define NEG_BIG -1e30f
#define SCL 0.15625f      // 1/(8*8*TAU)
#define SCL2 0.225396744f // SCL * log2(e)
#define C2 14.4269504f    // 10 * log2(e)
#define TILE_BYTES (64 * DK)  // 32 KB per 64-col fp8 tile
#define NRS 32                // row-sum slots (max chunks/panel)
#define NCS 32                // col-sum slots (panels)
#define NBLK 528              // sum_{I=0..31} (32-I)

typedef __attribute__((ext_vector_type(16))) float floatx16;
typedef __attribute__((ext_vector_type(8))) int intx8;

// ---------------- prep: normalize, fp8-pack into stacked Gn, init slots ---
// Permuted layout per row: byte kc2*32 + h*16 + t*8 + j holds original
// k = kc2*32 + t*16 + h*8 + j (MFMA K=64 operand = chunks 4i+h, 4i+2+h).
__global__ void __launch_bounds__(256) prep_kernel(
    const float* __restrict__ A, const float* __restrict__ Bv,
    unsigned char* __restrict__ Gn, float* __restrict__ diag,
    float* __restrict__ out, float* __restrict__ zbase,
    float* __restrict__ mbase) {
  const int gtid = blockIdx.x * 256 + threadIdx.x;
  if (gtid < 2) out[gtid] = 0.0f;
  // zbase = pRS(32*8192)+pCS(32*8192) zeros; mbase = pRM(32*4096)+
  // pCM(32*4096) = NEG_BIG
  for (int idx = gtid; idx < (NRS + NCS) * 8192; idx += 1024 * 256)
    zbase[idx] = 0.0f;
  for (int idx = gtid; idx < 64 * 4096; idx += 1024 * 256)
    mbase[idx] = NEG_BIG;

  const int w = threadIdx.x >> 6, lane = threadIdx.x & 63;
  const int row = blockIdx.x * 4 + w;
  const float4* pa4 = (const float4*)(A + (size_t)row * DK);
  const float4* pb4 = (const float4*)(Bv + (size_t)row * DK);
  float4 a0 = pa4[lane * 2], a1 = pa4[lane * 2 + 1];  // k = lane*8 .. +7
  float4 b0 = pb4[lane * 2], b1 = pb4[lane * 2 + 1];
  float ssa = a0.x * a0.x + a0.y * a0.y + a0.z * a0.z + a0.w * a0.w +
              a1.x * a1.x + a1.y * a1.y + a1.z * a1.z + a1.w * a1.w;
  float ssb = b0.x * b0.x + b0.y * b0.y + b0.z * b0.z + b0.w * b0.w +
              b1.x * b1.x + b1.y * b1.y + b1.z * b1.z + b1.w * b1.w;
  float sab = a0.x * b0.x + a0.y * b0.y + a0.z * b0.z + a0.w * b0.w +
              a1.x * b1.x + a1.y * b1.y + a1.z * b1.z + a1.w * b1.w;
#pragma unroll
  for (int off = 32; off > 0; off >>= 1) {
    ssa += __shfl_xor(ssa, off);
    ssb += __shfl_xor(ssb, off);
    sab += __shfl_xor(sab, off);
  }
  float na = fmaxf(sqrtf(ssa), 1e-12f);
  float nb = fmaxf(sqrtf(ssb), 1e-12f);
  const float s = 8.0f;  // fp8 pre-scale: keeps elems mid-range in e4m3
  float sa = s / na, sb = s / nb;
  const int doff = (lane >> 2) * 32 + (lane & 1) * 16 + ((lane >> 1) & 1) * 8;
  {
    int v0 = __builtin_amdgcn_cvt_pk_fp8_f32(a0.x * sa, a0.y * sa, 0, false);
    v0 = __builtin_amdgcn_cvt_pk_fp8_f32(a0.z * sa, a0.w * sa, v0, true);
    int v1 = __builtin_amdgcn_cvt_pk_fp8_f32(a1.x * sa, a1.y * sa, 0, false);
    v1 = __builtin_amdgcn_cvt_pk_fp8_f32(a1.z * sa, a1.w * sa, v1, true);
    int2 pv; pv.x = v0; pv.y = v1;
    *(int2*)(Gn + (size_t)row * DK + doff) = pv;
  }
  {
    int v0 = __builtin_amdgcn_cvt_pk_fp8_f32(b0.x * sb, b0.y * sb, 0, false);
    v0 = __builtin_amdgcn_cvt_pk_fp8_f32(b0.z * sb, b0.w * sb, v0, true);
    int v1 = __builtin_amdgcn_cvt_pk_fp8_f32(b1.x * sb, b1.y * sb, 0, false);
    v1 = __builtin_amdgcn_cvt_pk_fp8_f32(b1.z * sb, b1.w * sb, v1, true);
    int2 pv; pv.x = v0; pv.y = v1;
    *(int2*)(Gn + (size_t)(BN + row) * DK + doff) = pv;
  }
  if (lane == 0) diag[row] = (sab / (na * nb)) * 10.0f;  // exact fp32 /TAU
}

// ---------------- tiles: 256-row panels, 8 waves, 4 tiles/block -----------
__global__ void __launch_bounds__(512, 1) tiles_kernel(
    const unsigned char* __restrict__ Gn,
    float* __restrict__ pRS, float* __restrict__ pCS,
    float* __restrict__ pRM, float* __restrict__ pCM) {
  __shared__ __align__(16) unsigned char smem[TILE_BYTES];  // 32 KB
  __shared__ float cps[16][64];  // 4 KB: per-(wave,half) col sums
  __shared__ float cpm[16][64];  // 4 KB: per-(wave,half) col maxes

  // decode flat bid -> (I, chunk): panel I has exactly 32-I 4-tile chunks
  int bid = blockIdx.x, I = 0;
  for (;;) {
    const int nc = 32 - I;
    if (bid < nc) break;
    bid -= nc; ++I;
  }
  const int chunk = bid;
  const int j0 = 4 * I + chunk * 4;

  const int tid = threadIdx.x;
  const int lane = tid & 63, w = tid >> 6;   // w = 0..7
  const int n5 = lane & 31, h = lane >> 5;
  const int rbase = I * 256 + w * 32;
  const int w2h = w * 2 + h;                 // slice id, 0..15
  const bool arows = (I < 16);               // panel holds a-rows

  // row frags: lane n5 holds row rbase+n5 (once per block)
  intx8 aw[8];
  {
    const unsigned char* p = Gn + (size_t)(rbase + n5) * DK + h * 16;
#pragma unroll
    for (int i = 0; i < 8; ++i) {
      int4 c0 = *(const int4*)(p + i * 64);
      int4 c1 = *(const int4*)(p + i * 64 + 32);
      intx8 v = {c0.x, c0.y, c0.z, c0.w, c1.x, c1.y, c1.z, c1.w};
      aw[i] = v;
    }
  }

  // stage tile j (32 KB, 8 waves x 4 insts): DMA dest linear; 5-bit
  // swizzle via source (phys chunk p of col cl holds logical p^(cl&31))
  auto stage = [&](int j) {
    const int cb = j * 64;
#pragma unroll
    for (int ii = 0; ii < 4; ++ii) {
      const int cp = w * 4 + ii;
      const int cl = cp * 2 + h;
      const unsigned char* src =
          Gn + (size_t)(cb + cl) * DK + ((n5 ^ (cl & 31)) * 16);
      __builtin_amdgcn_global_load_lds(
          (const __attribute__((address_space(1))) void*)src,
          (__attribute__((address_space(3))) void*)(smem + cp * 1024),
          16, 0, 0);
    }
  };

  float l[16], mxr[16];
#pragma unroll
  for (int r = 0; r < 16; ++r) { l[r] = 0.f; mxr[r] = NEG_BIG; }

#pragma unroll 1
  for (int t = 0; t < 4; ++t) {
    const int j = j0 + t;
    stage(j);
    __syncthreads();  // tile-t reads of t-1 done pre-loop; DMA drained

    floatx16 acc[2];
#pragma unroll
    for (int cs = 0; cs < 2; ++cs)
#pragma unroll
      for (int r = 0; r < 16; ++r) acc[cs][r] = 0.f;

    const unsigned char* bbase = smem + (size_t)n5 * DK;
#pragma unroll
    for (int i = 0; i < 8; ++i) {
      const int p1 = ((4 * i + h) ^ n5) * 16;
      const int p2 = ((4 * i + 2 + h) ^ n5) * 16;
#pragma unroll
      for (int cs = 0; cs < 2; ++cs) {
        int4 b0 = *(const int4*)(bbase + cs * 32 * DK + p1);
        int4 b1 = *(const int4*)(bbase + cs * 32 * DK + p2);
        intx8 bw = {b0.x, b0.y, b0.z, b0.w, b1.x, b1.y, b1.z, b1.w};
        acc[cs] = __builtin_amdgcn_mfma_scale_f32_32x32x64_f8f6f4(
            aw[i], bw, acc[cs], 0, 0, 0, 0x7F7F7F7F, 0, 0x7F7F7F7F);
      }
    }

    // epilogue: variant-gated masks AND maxes.  acc elem (r,cs): row
    // rbase+(r&3)+8(r>>2)+4h, col cbase+cs*32+n5.
    const int cbase = j * 64;
    const bool diagp = ((j >> 2) == I);
    const bool lblp = arows && ((j >> 2) == 16 + I);
    const bool docmax = (j < 64);  // only a-cols need col max
    const int colg0 = cbase + n5, colg1 = cbase + 32 + n5;
    float csum0 = 0.f, csum1 = 0.f, cmax0 = NEG_BIG, cmax1 = NEG_BIG;

#define EPI_BODY(EXCL0_EXPR, EXCL1_EXPR, DO_R, DO_C)                        \
  _Pragma("unroll")                                                         \
  for (int r = 0; r < 16; ++r) {                                            \
    const int rowg = rbase + (r & 3) + 8 * (r >> 2) + 4 * h;                \
    (void)rowg;                                                             \
    {                                                                       \
      const float v = acc[0][r];                                            \
      const bool excl = (EXCL0_EXPR);                                       \
      const float e = excl ? 0.f : exp2f(fmaf(v, SCL2, -C2));               \
      l[r] += e; csum0 += e;                                                \
      if (DO_R || DO_C) {                                                   \
        const float vm = excl ? NEG_BIG : v;                                \
        if (DO_R) mxr[r] = fmaxf(mxr[r], vm);                               \
        if (DO_C) cmax0 = fmaxf(cmax0, vm);                                 \
      }                                                                     \
    }                                                                       \
    {                                                                       \
      const float v = acc[1][r];                                            \
      const bool excl = (EXCL1_EXPR);                                       \
      const float e = excl ? 0.f : exp2f(fmaf(v, SCL2, -C2));               \
      l[r] += e; csum1 += e;                                                \
      if (DO_R || DO_C) {                                                   \
        const float vm = excl ? NEG_BIG : v;                                \
        if (DO_R) mxr[r] = fmaxf(mxr[r], vm);                               \
        if (DO_C) cmax1 = fmaxf(cmax1, vm);                                 \
      }                                                                     \
    }                                                                       \
  }

    if (diagp) {
      if (arows) { EPI_BODY(colg0 <= rowg, colg1 <= rowg, true, true) }
      else       { EPI_BODY(colg0 <= rowg, colg1 <= rowg, false, false) }
    } else if (lblp) {
      EPI_BODY(colg0 == rowg + BN, colg1 == rowg + BN, true, false)
    } else if (arows) {
      if (docmax) { EPI_BODY(false, false, true, true) }
      else        { EPI_BODY(false, false, true, false) }
    } else {
      EPI_BODY(false, false, false, false)
    }
#undef EPI_BODY

    // col partials -> own slice (no shfl; h-halves = distinct slices)
    cps[w2h][n5] = csum0;
    cps[w2h][32 + n5] = csum1;
    if (docmax) {
      cpm[w2h][n5] = cmax0;
      cpm[w2h][32 + n5] = cmax1;
    }
    __syncthreads();  // tile reads done (buffer reusable) + slices visible
    if (tid < 64) {
      float s = 0.f;
#pragma unroll
      for (int q = 0; q < 16; ++q) s += cps[q][tid];
      pCS[(size_t)I * 8192 + cbase + tid] = s;
      if (docmax) {
        float m = cpm[0][tid];
#pragma unroll
        for (int q = 1; q < 16; ++q) m = fmaxf(m, cpm[q][tid]);
        pCM[(size_t)I * 4096 + cbase + tid] = m;
      }
    }
    // cps/cpm rewritten at t+1 only after the post-stage barrier, which
    // the merge threads reach only after their reads retire (lgkmcnt).
  }

  // one row reduce per block: across the 32 cols (lanes n5)
#pragma unroll
  for (int off = 1; off < 32; off <<= 1)
#pragma unroll
    for (int r = 0; r < 16; ++r) l[r] += __shfl_xor(l[r], off);
  if (arows) {
#pragma unroll
    for (int off = 1; off < 32; off <<= 1)
#pragma unroll
      for (int r = 0; r < 16; ++r)
        mxr[r] = fmaxf(mxr[r], __shfl_xor(mxr[r], off));
  }
  if (n5 == 0) {
#pragma unroll
    for (int r = 0; r < 16; ++r) {
      const int rowg = rbase + (r & 3) + 8 * (r >> 2) + 4 * h;
      pRS[(size_t)chunk * 8192 + rowg] = l[r];
      if (arows) pRM[(size_t)chunk * 4096 + rowg] = mxr[r];
    }
  }
}

// ---------------- finalize: 8 threads/row, parallel slot merge ------------
__global__ void __launch_bounds__(256) finalize_kernel(
    const float* __restrict__ pRS, const float* __restrict__ pCS,
    const float* __restrict__ pRM, const float* __restrict__ pCM,
    const float* __restrict__ diag, float* __restrict__ out) {
  const int k = threadIdx.x & 7;        // slot-share index, 0..7
  const int r = threadIdx.x >> 3;       // row within block, 0..31
  const int i = blockIdx.x * 32 + r;    // label index, 0..4095

  float SA = 0.f, SB = 0.f, MA = NEG_BIG;
#pragma unroll
  for (int q = 0; q < 4; ++q) {         // pRS/pRM: 32 slots, 4 per thread
    const int s = k * 4 + q;
    SA += pRS[(size_t)s * 8192 + i];
    SB += pRS[(size_t)s * 8192 + BN + i];
    MA = fmaxf(MA, pRM[(size_t)s * 4096 + i]);
  }
#pragma unroll
  for (int q = 0; q < 4; ++q) {         // pCS: 32 slots, 4 per thread
    const int s = k * 4 + q;
    SA += pCS[(size_t)s * 8192 + i];
    SB += pCS[(size_t)s * 8192 + BN + i];
  }
#pragma unroll
  for (int q = 0; q < 2; ++q) {         // pCM: 16 used slots, 2 per thread
    const int s = k * 2 + q;
    MA = fmaxf(MA, pCM[(size_t)s * 4096 + i]);
  }
  // combine the 8-thread group (lanes k=0..7 of the same row)
#pragma unroll
  for (int off = 1; off < 8; off <<= 1) {
    SA += __shfl_xor(SA, off);
    SB += __shfl_xor(SB, off);
    MA = fmaxf(MA, __shfl_xor(MA, off));
  }

  float lossi = 0.f, corr = 0.f;
  if (k == 0) {
    const float d = diag[i];
    const float eL = exp2f(fmaf(d, 1.44269504f, -C2));  // exp(d-10)
    lossi = (10.0f + logf(SA + eL) - d) + (10.0f + logf(SB + eL) - d);
    corr = (d >= MA * SCL) ? 1.f : 0.f;  // argmax(full_a)==label
  }
#pragma unroll
  for (int off = 32; off > 0; off >>= 1) {
    lossi += __shfl_xor(lossi, off);
    corr += __shfl_xor(corr, off);
  }
  __shared__ float sred[2][4];
  if ((threadIdx.x & 63) == 0) {
    int w = threadIdx.x >> 6;
    sred[0][w] = lossi; sred[1][w] = corr;
  }
  __syncthreads();
  if (threadIdx.x == 0) {
    float ls = sred[0][0] + sred[0][1] + sred[0][2] + sred[0][3];
    float cs = sred[1][0] + sred[1][1] + sred[1][2] + sred[1][3];
    atomicAdd(&out[0], ls * (1.0f / 8192.0f));    // mean over rows, /2
    atomicAdd(&out[1], cs * (100.0f / 4096.0f));  // accuracy %
  }
}

extern "C" void kernel_launch(void* const* d_in, const int* in_sizes, int n_in,
                              void* d_out, int out_size, void* d_ws, size_t ws_size,
                              hipStream_t stream) {
  const float* A = (const float*)d_in[0];
  const float* Bv = (const float*)d_in[1];
  unsigned char* Gn = (unsigned char*)d_ws;          // 8192x512 fp8 (a;b)
  float* diag = (float*)(Gn + (size_t)8192 * DK);    // 4096 f32
  float* pRS = diag + BN;                            // [32][8192]
  float* pCS = pRS + NRS * 8192;                     // [32][8192]
  float* pRM = pCS + NCS * 8192;                     // [32][4096]
  float* pCM = pRM + 32 * 4096;                      // [32][4096]
  float* out = (float*)d_out;

  prep_kernel<<<BN / 4, 256, 0, stream>>>(A, Bv, Gn, diag, out, pRS, pRM);
  tiles_kernel<<<NBLK, 512, 0, stream>>>(Gn, pRS, pCS, pRM, pCM);
  finalize_kernel<<<BN / 32, 256, 0, stream>>>(pRS, pCS, pRM, pCM, diag, out);
}

// Round 16
// 131.922 us; speedup vs baseline: 1.0396x; 1.0396x over previous
//
#include <hip/hip_runtime.h>
#include <stdint.h>

// SimCLR loss, B=4096, D=512, TAU=0.1.  out[0]=loss, out[1]=acc(%).
//
// Round 26: 8-wave blocks, THIRD attempt -- live set cut below 128.
// R24 (512,2) and R25 (512,1) produced byte-identical codegen: VGPR pinned
// 128, ~36MB scratch -- the allocator won't go above 128 for this 512-
// thread kernel regardless of bounds, so the only route is to FIT 128.
// Change vs R25: cs-SPLIT.  The two 32-col halves of each tile are
// processed in two sequential passes (#pragma unroll 1, single floatx16
// acc per pass; col partials stored to their LDS slice inside the pass --
// no cross-pass scalars, no runtime-indexed register arrays).  Peak live:
// aw 64 + acc 16 + l 16 + mxr 16 + temps ~= 130 (vs ~190 with acc[2]).
// ILP loss from unsplit chains is exactly what 2-waves/SIMD residency
// should hide -- this finally runs the residency experiment clean.
// Everything else = R24/R25: 32 panels x 256 rows, 8 waves x 32 rows,
// 4 tiles/block, 528 balanced blocks, 5-bit swizzle, variant-gated
// epilogue, 40KB LDS, parallel finalize.

#define BN 4096
#define DK 512            // K elements = bytes per row in fp8
#define NEG_BIG -1e30f
#define SCL 0.15625f      // 1/(8*8*TAU)
#define SCL2 0.225396744f // SCL * log2(e)
#define C2 14.4269504f    // 10 * log2(e)
#define TILE_BYTES (64 * DK)  // 32 KB per 64-col fp8 tile
#define NRS 32                // row-sum slots (max chunks/panel)
#define NCS 32                // col-sum slots (panels)
#define NBLK 528              // sum_{I=0..31} (32-I)

typedef __attribute__((ext_vector_type(16))) float floatx16;
typedef __attribute__((ext_vector_type(8))) int intx8;

// ---------------- prep: normalize, fp8-pack into stacked Gn, init slots ---
// Permuted layout per row: byte kc2*32 + h*16 + t*8 + j holds original
// k = kc2*32 + t*16 + h*8 + j (MFMA K=64 operand = chunks 4i+h, 4i+2+h).
__global__ void __launch_bounds__(256) prep_kernel(
    const float* __restrict__ A, const float* __restrict__ Bv,
    unsigned char* __restrict__ Gn, float* __restrict__ diag,
    float* __restrict__ out, float* __restrict__ zbase,
    float* __restrict__ mbase) {
  const int gtid = blockIdx.x * 256 + threadIdx.x;
  if (gtid < 2) out[gtid] = 0.0f;
  // zbase = pRS(32*8192)+pCS(32*8192) zeros; mbase = pRM(32*4096)+
  // pCM(32*4096) = NEG_BIG
  for (int idx = gtid; idx < (NRS + NCS) * 8192; idx += 1024 * 256)
    zbase[idx] = 0.0f;
  for (int idx = gtid; idx < 64 * 4096; idx += 1024 * 256)
    mbase[idx] = NEG_BIG;

  const int w = threadIdx.x >> 6, lane = threadIdx.x & 63;
  const int row = blockIdx.x * 4 + w;
  const float4* pa4 = (const float4*)(A + (size_t)row * DK);
  const float4* pb4 = (const float4*)(Bv + (size_t)row * DK);
  float4 a0 = pa4[lane * 2], a1 = pa4[lane * 2 + 1];  // k = lane*8 .. +7
  float4 b0 = pb4[lane * 2], b1 = pb4[lane * 2 + 1];
  float ssa = a0.x * a0.x + a0.y * a0.y + a0.z * a0.z + a0.w * a0.w +
              a1.x * a1.x + a1.y * a1.y + a1.z * a1.z + a1.w * a1.w;
  float ssb = b0.x * b0.x + b0.y * b0.y + b0.z * b0.z + b0.w * b0.w +
              b1.x * b1.x + b1.y * b1.y + b1.z * b1.z + b1.w * b1.w;
  float sab = a0.x * b0.x + a0.y * b0.y + a0.z * b0.z + a0.w * b0.w +
              a1.x * b1.x + a1.y * b1.y + a1.z * b1.z + a1.w * b1.w;
#pragma unroll
  for (int off = 32; off > 0; off >>= 1) {
    ssa += __shfl_xor(ssa, off);
    ssb += __shfl_xor(ssb, off);
    sab += __shfl_xor(sab, off);
  }
  float na = fmaxf(sqrtf(ssa), 1e-12f);
  float nb = fmaxf(sqrtf(ssb), 1e-12f);
  const float s = 8.0f;  // fp8 pre-scale: keeps elems mid-range in e4m3
  float sa = s / na, sb = s / nb;
  const int doff = (lane >> 2) * 32 + (lane & 1) * 16 + ((lane >> 1) & 1) * 8;
  {
    int v0 = __builtin_amdgcn_cvt_pk_fp8_f32(a0.x * sa, a0.y * sa, 0, false);
    v0 = __builtin_amdgcn_cvt_pk_fp8_f32(a0.z * sa, a0.w * sa, v0, true);
    int v1 = __builtin_amdgcn_cvt_pk_fp8_f32(a1.x * sa, a1.y * sa, 0, false);
    v1 = __builtin_amdgcn_cvt_pk_fp8_f32(a1.z * sa, a1.w * sa, v1, true);
    int2 pv; pv.x = v0; pv.y = v1;
    *(int2*)(Gn + (size_t)row * DK + doff) = pv;
  }
  {
    int v0 = __builtin_amdgcn_cvt_pk_fp8_f32(b0.x * sb, b0.y * sb, 0, false);
    v0 = __builtin_amdgcn_cvt_pk_fp8_f32(b0.z * sb, b0.w * sb, v0, true);
    int v1 = __builtin_amdgcn_cvt_pk_fp8_f32(b1.x * sb, b1.y * sb, 0, false);
    v1 = __builtin_amdgcn_cvt_pk_fp8_f32(b1.z * sb, b1.w * sb, v1, true);
    int2 pv; pv.x = v0; pv.y = v1;
    *(int2*)(Gn + (size_t)(BN + row) * DK + doff) = pv;
  }
  if (lane == 0) diag[row] = (sab / (na * nb)) * 10.0f;  // exact fp32 /TAU
}

// ---------------- tiles: 256-row panels, 8 waves, 4 tiles, cs-split -------
__global__ void __launch_bounds__(512, 1) tiles_kernel(
    const unsigned char* __restrict__ Gn,
    float* __restrict__ pRS, float* __restrict__ pCS,
    float* __restrict__ pRM, float* __restrict__ pCM) {
  __shared__ __align__(16) unsigned char smem[TILE_BYTES];  // 32 KB
  __shared__ float cps[16][64];  // 4 KB: per-(wave,half) col sums
  __shared__ float cpm[16][64];  // 4 KB: per-(wave,half) col maxes

  // decode flat bid -> (I, chunk): panel I has exactly 32-I 4-tile chunks
  int bid = blockIdx.x, I = 0;
  for (;;) {
    const int nc = 32 - I;
    if (bid < nc) break;
    bid -= nc; ++I;
  }
  const int chunk = bid;
  const int j0 = 4 * I + chunk * 4;

  const int tid = threadIdx.x;
  const int lane = tid & 63, w = tid >> 6;   // w = 0..7
  const int n5 = lane & 31, h = lane >> 5;
  const int rbase = I * 256 + w * 32;
  const int w2h = w * 2 + h;                 // slice id, 0..15
  const bool arows = (I < 16);               // panel holds a-rows

  // row frags: lane n5 holds row rbase+n5 (once per block)
  intx8 aw[8];
  {
    const unsigned char* p = Gn + (size_t)(rbase + n5) * DK + h * 16;
#pragma unroll
    for (int i = 0; i < 8; ++i) {
      int4 c0 = *(const int4*)(p + i * 64);
      int4 c1 = *(const int4*)(p + i * 64 + 32);
      intx8 v = {c0.x, c0.y, c0.z, c0.w, c1.x, c1.y, c1.z, c1.w};
      aw[i] = v;
    }
  }

  // stage tile j (32 KB, 8 waves x 4 insts): DMA dest linear; 5-bit
  // swizzle via source (phys chunk p of col cl holds logical p^(cl&31))
  auto stage = [&](int j) {
    const int cb = j * 64;
#pragma unroll
    for (int ii = 0; ii < 4; ++ii) {
      const int cp = w * 4 + ii;
      const int cl = cp * 2 + h;
      const unsigned char* src =
          Gn + (size_t)(cb + cl) * DK + ((n5 ^ (cl & 31)) * 16);
      __builtin_amdgcn_global_load_lds(
          (const __attribute__((address_space(1))) void*)src,
          (__attribute__((address_space(3))) void*)(smem + cp * 1024),
          16, 0, 0);
    }
  };

  float l[16], mxr[16];
#pragma unroll
  for (int r = 0; r < 16; ++r) { l[r] = 0.f; mxr[r] = NEG_BIG; }

#pragma unroll 1
  for (int t = 0; t < 4; ++t) {
    const int j = j0 + t;
    stage(j);
    __syncthreads();  // tile-t reads of t-1 done pre-loop; DMA drained

    const int cbase = j * 64;
    const bool diagp = ((j >> 2) == I);
    const bool lblp = arows && ((j >> 2) == 16 + I);
    const bool docmax = (j < 64);  // only a-cols need col max

    // ---- cs-split: two sequential 32-col passes, one acc each ----------
#pragma unroll 1
    for (int cs = 0; cs < 2; ++cs) {
      floatx16 acc;
#pragma unroll
      for (int r = 0; r < 16; ++r) acc[r] = 0.f;

      const unsigned char* bbase = smem + (size_t)(cs * 32 * DK + n5 * DK);
#pragma unroll
      for (int i = 0; i < 8; ++i) {
        const int p1 = ((4 * i + h) ^ n5) * 16;
        const int p2 = ((4 * i + 2 + h) ^ n5) * 16;
        int4 b0 = *(const int4*)(bbase + p1);
        int4 b1 = *(const int4*)(bbase + p2);
        intx8 bw = {b0.x, b0.y, b0.z, b0.w, b1.x, b1.y, b1.z, b1.w};
        acc = __builtin_amdgcn_mfma_scale_f32_32x32x64_f8f6f4(
            aw[i], bw, acc, 0, 0, 0, 0x7F7F7F7F, 0, 0x7F7F7F7F);
      }

      // epilogue for this 32-col half; acc elem r: row rbase+(r&3)+
      // 8(r>>2)+4h, col cbase+cs*32+n5.
      const int colg = cbase + cs * 32 + n5;
      float cs_sum = 0.f, cs_max = NEG_BIG;

#define EPI1(EXCL_EXPR, DO_R, DO_C)                                         \
  _Pragma("unroll")                                                         \
  for (int r = 0; r < 16; ++r) {                                            \
    const int rowg = rbase + (r & 3) + 8 * (r >> 2) + 4 * h;                \
    (void)rowg;                                                             \
    const float v = acc[r];                                                 \
    const bool excl = (EXCL_EXPR);                                          \
    const float e = excl ? 0.f : exp2f(fmaf(v, SCL2, -C2));                 \
    l[r] += e; cs_sum += e;                                                 \
    if (DO_R || DO_C) {                                                     \
      const float vm = excl ? NEG_BIG : v;                                  \
      if (DO_R) mxr[r] = fmaxf(mxr[r], vm);                                 \
      if (DO_C) cs_max = fmaxf(cs_max, vm);                                 \
    }                                                                       \
  }

      if (diagp) {
        if (arows) { EPI1(colg <= rowg, true, true) }
        else       { EPI1(colg <= rowg, false, false) }
      } else if (lblp) {
        EPI1(colg == rowg + BN, true, false)
      } else if (arows) {
        if (docmax) { EPI1(false, true, true) }
        else        { EPI1(false, true, false) }
      } else {
        EPI1(false, false, false)
      }
#undef EPI1

      // col partials -> own slice (no shfl; h-halves = distinct slices)
      cps[w2h][cs * 32 + n5] = cs_sum;
      if (docmax) cpm[w2h][cs * 32 + n5] = cs_max;
    }

    __syncthreads();  // tile reads done (buffer reusable) + slices visible
    if (tid < 64) {
      float s = 0.f;
#pragma unroll
      for (int q = 0; q < 16; ++q) s += cps[q][tid];
      pCS[(size_t)I * 8192 + cbase + tid] = s;
      if (docmax) {
        float m = cpm[0][tid];
#pragma unroll
        for (int q = 1; q < 16; ++q) m = fmaxf(m, cpm[q][tid]);
        pCM[(size_t)I * 4096 + cbase + tid] = m;
      }
    }
    // cps/cpm rewritten at t+1 only after the post-stage barrier; merge
    // readers' loads retire before they reach that barrier.
  }

  // one row reduce per block: across the 32 cols (lanes n5)
#pragma unroll
  for (int off = 1; off < 32; off <<= 1)
#pragma unroll
    for (int r = 0; r < 16; ++r) l[r] += __shfl_xor(l[r], off);
  if (arows) {
#pragma unroll
    for (int off = 1; off < 32; off <<= 1)
#pragma unroll
      for (int r = 0; r < 16; ++r)
        mxr[r] = fmaxf(mxr[r], __shfl_xor(mxr[r], off));
  }
  if (n5 == 0) {
#pragma unroll
    for (int r = 0; r < 16; ++r) {
      const int rowg = rbase + (r & 3) + 8 * (r >> 2) + 4 * h;
      pRS[(size_t)chunk * 8192 + rowg] = l[r];
      if (arows) pRM[(size_t)chunk * 4096 + rowg] = mxr[r];
    }
  }
}

// ---------------- finalize: 8 threads/row, parallel slot merge ------------
__global__ void __launch_bounds__(256) finalize_kernel(
    const float* __restrict__ pRS, const float* __restrict__ pCS,
    const float* __restrict__ pRM, const float* __restrict__ pCM,
    const float* __restrict__ diag, float* __restrict__ out) {
  const int k = threadIdx.x & 7;        // slot-share index, 0..7
  const int r = threadIdx.x >> 3;       // row within block, 0..31
  const int i = blockIdx.x * 32 + r;    // label index, 0..4095

  float SA = 0.f, SB = 0.f, MA = NEG_BIG;
#pragma unroll
  for (int q = 0; q < 4; ++q) {         // pRS/pRM: 32 slots, 4 per thread
    const int s = k * 4 + q;
    SA += pRS[(size_t)s * 8192 + i];
    SB += pRS[(size_t)s * 8192 + BN + i];
    MA = fmaxf(MA, pRM[(size_t)s * 4096 + i]);
  }
#pragma unroll
  for (int q = 0; q < 4; ++q) {         // pCS: 32 slots, 4 per thread
    const int s = k * 4 + q;
    SA += pCS[(size_t)s * 8192 + i];
    SB += pCS[(size_t)s * 8192 + BN + i];
  }
#pragma unroll
  for (int q = 0; q < 2; ++q) {         // pCM: 16 used slots, 2 per thread
    const int s = k * 2 + q;
    MA = fmaxf(MA, pCM[(size_t)s * 4096 + i]);
  }
  // combine the 8-thread group (lanes k=0..7 of the same row)
#pragma unroll
  for (int off = 1; off < 8; off <<= 1) {
    SA += __shfl_xor(SA, off);
    SB += __shfl_xor(SB, off);
    MA = fmaxf(MA, __shfl_xor(MA, off));
  }

  float lossi = 0.f, corr = 0.f;
  if (k == 0) {
    const float d = diag[i];
    const float eL = exp2f(fmaf(d, 1.44269504f, -C2));  // exp(d-10)
    lossi = (10.0f + logf(SA + eL) - d) + (10.0f + logf(SB + eL) - d);
    corr = (d >= MA * SCL) ? 1.f : 0.f;  // argmax(full_a)==label
  }
#pragma unroll
  for (int off = 32; off > 0; off >>= 1) {
    lossi += __shfl_xor(lossi, off);
    corr += __shfl_xor(corr, off);
  }
  __shared__ float sred[2][4];
  if ((threadIdx.x & 63) == 0) {
    int w = threadIdx.x >> 6;
    sred[0][w] = lossi; sred[1][w] = corr;
  }
  __syncthreads();
  if (threadIdx.x == 0) {
    float ls = sred[0][0] + sred[0][1] + sred[0][2] + sred[0][3];
    float cs = sred[1][0] + sred[1][1] + sred[1][2] + sred[1][3];
    atomicAdd(&out[0], ls * (1.0f / 8192.0f));    // mean over rows, /2
    atomicAdd(&out[1], cs * (100.0f / 4096.0f));  // accuracy %
  }
}

extern "C" void kernel_launch(void* const* d_in, const int* in_sizes, int n_in,
                              void* d_out, int out_size, void* d_ws, size_t ws_size,
                              hipStream_t stream) {
  const float* A = (const float*)d_in[0];
  const float* Bv = (const float*)d_in[1];
  unsigned char* Gn = (unsigned char*)d_ws;          // 8192x512 fp8 (a;b)
  float* diag = (float*)(Gn + (size_t)8192 * DK);    // 4096 f32
  float* pRS = diag + BN;                            // [32][8192]
  float* pCS = pRS + NRS * 8192;                     // [32][8192]
  float* pRM = pCS + NCS * 8192;                     // [32][4096]
  float* pCM = pRM + 32 * 4096;                      // [32][4096]
  float* out = (float*)d_out;

  prep_kernel<<<BN / 4, 256, 0, stream>>>(A, Bv, Gn, diag, out, pRS, pRM);
  tiles_kernel<<<NBLK, 512, 0, stream>>>(Gn, pRS, pCS, pRM, pCM);
  finalize_kernel<<<BN / 32, 256, 0, stream>>>(pRS, pCS, pRM, pCM, diag, out);
}